// Round 1
// baseline (1646.079 us; speedup 1.0000x reference)
//
#include <hip/hip_runtime.h>
#include <cstdint>

#define NEG_SLOPE 0.2f
#define HEADS 4
#define CH 64
#define HC 256
#define F_IN 260
#define NGRAPH 128

__device__ __forceinline__ float seluf(float x){
    const float sc=1.0507009873554805f, al=1.6732632423543772f;
    return x>0.f ? sc*x : sc*al*(__expf(x)-1.f);
}
__device__ __forceinline__ unsigned fenc(float x){
    unsigned u=__float_as_uint(x);
    return (u&0x80000000u)? ~u : (u|0x80000000u);
}
__device__ __forceinline__ float fdec(unsigned e){
    unsigned u = (e&0x80000000u)? (e&0x7fffffffu) : ~e;
    return __uint_as_float(u);
}

__global__ void fill_u32_kernel(unsigned* p, unsigned v, int n){
    int i = blockIdx.x*blockDim.x + threadIdx.x;
    for (; i<n; i += gridDim.x*blockDim.x) p[i]=v;
}

__global__ void degree_kernel(const int* __restrict__ ei, int* __restrict__ deg, int E){
    int i = blockIdx.x*blockDim.x+threadIdx.x;
    for (; i<E; i+=gridDim.x*blockDim.x) atomicAdd(&deg[ei[E+i]], 1);
}

__global__ void scan_ph1(const int* __restrict__ deg, int* __restrict__ bsum, int N){
    __shared__ int sd[256];
    int base = blockIdx.x*1024;
    int t = threadIdx.x;
    int tot=0;
    for(int u=0;u<4;u++){ int i = base + t*4+u; tot += (i<N)? deg[i]:0; }
    sd[t]=tot; __syncthreads();
    for(int off=128; off; off>>=1){ if(t<off) sd[t]+=sd[t+off]; __syncthreads(); }
    if(t==0) bsum[blockIdx.x]=sd[0];
}
__global__ void scan_ph2(int* bsum, int nb, int* rowptr, int N, int E){
    if(threadIdx.x==0 && blockIdx.x==0){
        int run=0;
        for(int b=0;b<nb;b++){ int v=bsum[b]; bsum[b]=run; run+=v; }
        rowptr[N]=E;
    }
}
__global__ void scan_ph3(const int* __restrict__ deg, const int* __restrict__ bsum,
                         int* __restrict__ rowptr, int N){
    __shared__ int sd[256];
    int base = blockIdx.x*1024;
    int t = threadIdx.x;
    int v[4]; int tot=0;
    for(int u=0;u<4;u++){ int i=base+t*4+u; v[u] = (i<N)? deg[i]:0; tot+=v[u]; }
    sd[t]=tot; __syncthreads();
    for(int off=1; off<256; off<<=1){
        int add = (t>=off)? sd[t-off] : 0;
        __syncthreads();
        sd[t] += add;
        __syncthreads();
    }
    int pre = bsum[blockIdx.x] + ((t==0)?0: sd[t-1]);
    for(int u=0;u<4;u++){ int i=base+t*4+u; if(i<N){ rowptr[i]=pre; pre+=v[u]; } }
}

__global__ void scatter_kernel(const int* __restrict__ ei, const int* __restrict__ rowptr,
                               int* __restrict__ fil, int* __restrict__ col, int E){
    int i = blockIdx.x*blockDim.x+threadIdx.x;
    for(; i<E; i+=gridDim.x*blockDim.x){
        int s = ei[i], d = ei[E+i];
        int p = atomicAdd(&fil[d],1);
        col[rowptr[d]+p] = s;
    }
}

// C[M,NC] = A[M,K] @ B[K,NC] (+bias) (+selu).  BM=128 BN=64 BK=16, 256 thr, 8x4/thread.
__global__ __launch_bounds__(256) void gemm_kernel(
    const float* __restrict__ A, const float* __restrict__ Bm,
    const float* __restrict__ bias, float* __restrict__ Cm,
    int M, int K, int NC, int act)
{
    __shared__ float As[16][129];
    __shared__ float Bs[16][64];
    int tid = threadIdx.x;
    int tx = tid & 15, ty = tid >> 4;
    int row0 = blockIdx.x * 128, col0 = blockIdx.y * 64;
    float acc[8][4];
    #pragma unroll
    for(int i=0;i<8;i++)
        #pragma unroll
        for(int j=0;j<4;j++) acc[i][j]=0.f;
    int ktiles = (K+15)/16;
    for(int kt=0; kt<ktiles; kt++){
        int k0 = kt*16;
        #pragma unroll
        for(int i=0;i<8;i++){
            int idx = tid + i*256;
            int m = idx >> 4, k = idx & 15;
            int gr = row0 + m, gk = k0 + k;
            As[k][m] = (gr < M && gk < K) ? A[(size_t)gr*K + gk] : 0.f;
        }
        #pragma unroll
        for(int i=0;i<4;i++){
            int idx = tid + i*256;
            int n = idx & 63, k = idx >> 6;
            int gk = k0 + k;
            Bs[k][n] = (gk < K) ? Bm[(size_t)gk*NC + col0 + n] : 0.f;
        }
        __syncthreads();
        #pragma unroll
        for(int k=0;k<16;k++){
            float a[8], b[4];
            #pragma unroll
            for(int i=0;i<8;i++) a[i]=As[k][ty*8+i];
            #pragma unroll
            for(int j=0;j<4;j++) b[j]=Bs[k][tx*4+j];
            #pragma unroll
            for(int i=0;i<8;i++)
                #pragma unroll
                for(int j=0;j<4;j++) acc[i][j] = fmaf(a[i], b[j], acc[i][j]);
        }
        __syncthreads();
    }
    #pragma unroll
    for(int i=0;i<8;i++){
        int gr = row0 + ty*8 + i;
        if (gr < M){
            #pragma unroll
            for(int j=0;j<4;j++){
                int gc = col0 + tx*4 + j;
                float v = acc[i][j];
                if (bias) v += bias[gc];
                if (act) v = seluf(v);
                Cm[(size_t)gr*NC + gc] = v;
            }
        }
    }
}

// per-node attention scores: ss[n][h] = sum_c h[n,h,c]*asrc[h,c]; sd likewise with adst
__global__ void scores_kernel(const float* __restrict__ h, const float* __restrict__ asrc,
                              const float* __restrict__ adst, float* __restrict__ ss,
                              float* __restrict__ sdv, int N){
    int node = blockIdx.x*4 + (threadIdx.x>>6);
    int lane = threadIdx.x & 63;
    if (node >= N) return;
    const float* row = h + (size_t)node*HC;
    float ts[4], td[4];
    #pragma unroll
    for(int hh=0;hh<4;hh++){
        float v = row[hh*64+lane];
        ts[hh] = v * asrc[hh*64+lane];
        td[hh] = v * adst[hh*64+lane];
    }
    #pragma unroll
    for(int off=32; off; off>>=1){
        #pragma unroll
        for(int hh=0;hh<4;hh++){
            ts[hh] += __shfl_down(ts[hh], off);
            td[hh] += __shfl_down(td[hh], off);
        }
    }
    if(lane==0){
        #pragma unroll
        for(int hh=0;hh<4;hh++){ ss[node*4+hh]=ts[hh]; sdv[node*4+hh]=td[hh]; }
    }
}

// one wave per dst node, online softmax over in-edges + implicit self-loop
__global__ void aggregate_kernel(const float* __restrict__ h, const float* __restrict__ ss,
                                 const float* __restrict__ sdv, const int* __restrict__ rowptr,
                                 const int* __restrict__ col, const float* __restrict__ bias,
                                 float* __restrict__ outp, int N){
    int node = blockIdx.x*4 + (threadIdx.x>>6);
    int lane = threadIdx.x & 63;
    if (node >= N) return;
    float ad[4], m[4], s[4], acc[4];
    #pragma unroll
    for(int hh=0;hh<4;hh++) ad[hh] = sdv[node*4+hh];
    #pragma unroll
    for(int hh=0;hh<4;hh++){
        float e = ss[node*4+hh] + ad[hh];
        e = e>0.f? e : NEG_SLOPE*e;
        m[hh]=e; s[hh]=1.f;
        acc[hh] = h[(size_t)node*HC + hh*64 + lane];
    }
    int jb = rowptr[node], je = rowptr[node+1];
    for(int j=jb;j<je;j++){
        int sc = col[j];
        const float* srow = h + (size_t)sc*HC;
        #pragma unroll
        for(int hh=0;hh<4;hh++){
            float v = srow[hh*64+lane];
            float e = ss[sc*4+hh] + ad[hh];
            e = e>0.f? e : NEG_SLOPE*e;
            float mn = fmaxf(m[hh], e);
            float c1 = __expf(m[hh]-mn);
            float p  = __expf(e-mn);
            s[hh] = s[hh]*c1 + p;
            acc[hh] = acc[hh]*c1 + p*v;
            m[hh] = mn;
        }
    }
    #pragma unroll
    for(int hh=0;hh<4;hh++)
        outp[(size_t)node*HC + hh*64 + lane] = acc[hh]/s[hh] + bias[hh*64+lane];
}

__global__ void count_kernel(const int* __restrict__ batch, int* __restrict__ cnt, int N){
    int i = blockIdx.x*blockDim.x+threadIdx.x;
    for(; i<N; i+=gridDim.x*blockDim.x) atomicAdd(&cnt[batch[i]],1);
}

__global__ void pool_acc_kernel(const float* __restrict__ hs, const int* __restrict__ batch,
                                float* __restrict__ psum, unsigned* __restrict__ pmax, int N){
    int i = blockIdx.x*blockDim.x+threadIdx.x;
    int total = N*64;
    for(; i<total; i+=gridDim.x*blockDim.x){
        int n = i>>6, c = i&63;
        float v = hs[i];
        int g = batch[n];
        atomicAdd(&psum[g*64+c], v);
        atomicMax(&pmax[g*64+c], fenc(v));
    }
}

__global__ void pool_final_kernel(const float* __restrict__ psum, const unsigned* __restrict__ pmax,
                                  const int* __restrict__ cnt, float* __restrict__ x, int G){
    int i = blockIdx.x*blockDim.x+threadIdx.x;
    if (i >= G*64) return;
    int g=i>>6, c=i&63;
    float cf = fmaxf((float)cnt[g], 1.f);
    x[g*128 + c] = psum[i]/cf;
    x[g*128 + 64 + c] = fdec(pmax[i]);
}

__global__ __launch_bounds__(128) void head_kernel(
    const float* __restrict__ x1, const float* __restrict__ x2,
    const float* __restrict__ sw, const float* __restrict__ sb,
    const float* __restrict__ w1, const float* __restrict__ b1,
    const float* __restrict__ w2, const float* __restrict__ b2,
    const float* __restrict__ w3, const float* __restrict__ b3,
    const float* __restrict__ rw, const float* __restrict__ rb,
    float* __restrict__ out)
{
    int g = blockIdx.x, t = threadIdx.x;
    __shared__ float v[256], z1[128], z2[64], z3[64], z4[64];
    v[t] = x1[g*128+t];
    v[128+t] = x2[g*128+t];
    __syncthreads();
    float a = sb[t];
    for(int k=0;k<256;k++) a = fmaf(v[k], sw[k*128+t], a);
    z1[t] = a;
    __syncthreads();
    if(t<64){
        float a2 = b1[t];
        for(int k=0;k<128;k++) a2 = fmaf(z1[k], w1[k*64+t], a2);
        z2[t] = seluf(a2);
    }
    __syncthreads();
    if(t<64){
        float a3 = b2[t];
        for(int k=0;k<64;k++) a3 = fmaf(z2[k], w2[k*64+t], a3);
        z3[t] = seluf(a3);
    }
    __syncthreads();
    if(t<64){
        float a4 = b3[t];
        for(int k=0;k<64;k++) a4 = fmaf(z3[k], w3[k*64+t], a4);
        z4[t] = seluf(a4);
    }
    __syncthreads();
    if(t<32){
        float a5 = rb[t];
        for(int k=0;k<64;k++) a5 = fmaf(z4[k], rw[k*32+t], a5);
        out[g*32+t] = a5;
    }
}

extern "C" void kernel_launch(void* const* d_in, const int* in_sizes, int n_in,
                              void* d_out, int out_size, void* d_ws, size_t ws_size,
                              hipStream_t stream)
{
    const float* x    = (const float*)d_in[0];
    const int*   ei   = (const int*)d_in[1];
    const int*   batch= (const int*)d_in[2];
    const float* g1w  = (const float*)d_in[3];
    const float* g1as = (const float*)d_in[4];
    const float* g1ad = (const float*)d_in[5];
    const float* g1b  = (const float*)d_in[6];
    const float* l1w  = (const float*)d_in[7];
    const float* l1b  = (const float*)d_in[8];
    const float* g2w  = (const float*)d_in[9];
    const float* g2as = (const float*)d_in[10];
    const float* g2ad = (const float*)d_in[11];
    const float* g2b  = (const float*)d_in[12];
    const float* l2w  = (const float*)d_in[13];
    const float* l2b  = (const float*)d_in[14];
    const float* sw   = (const float*)d_in[15];
    const float* sb   = (const float*)d_in[16];
    const float* s1w  = (const float*)d_in[17];
    const float* s1b  = (const float*)d_in[18];
    const float* s2w  = (const float*)d_in[19];
    const float* s2b  = (const float*)d_in[20];
    const float* s3w  = (const float*)d_in[21];
    const float* s3b  = (const float*)d_in[22];
    const float* rw   = (const float*)d_in[23];
    const float* rb   = (const float*)d_in[24];
    float* out = (float*)d_out;

    const int N = in_sizes[0] / F_IN;
    const int E = in_sizes[1] / 2;
    const int G = NGRAPH;

    char* ws = (char*)d_ws;
    size_t off = 0;
    auto alloc = [&](size_t bytes)->void*{
        void* p = ws + off;
        off += (bytes + 255) & ~(size_t)255;
        return p;
    };
    int* deg     = (int*)alloc((size_t)N*4);
    int* fil     = (int*)alloc((size_t)N*4);
    int* rowptr  = (int*)alloc(((size_t)N+1)*4);
    int* col     = (int*)alloc((size_t)E*4);
    int* bsum    = (int*)alloc(1024);
    float* A     = (float*)alloc((size_t)N*HC*4);
    float* Bb    = (float*)alloc((size_t)N*HC*4);
    float* HS    = (float*)alloc((size_t)N*CH*4);
    float* SCS   = (float*)alloc((size_t)N*HEADS*4);
    float* SCD   = (float*)alloc((size_t)N*HEADS*4);
    int* cnt     = (int*)alloc((size_t)G*4);
    float* PS1   = (float*)alloc((size_t)G*64*4);
    unsigned* PM1= (unsigned*)alloc((size_t)G*64*4);
    float* PS2   = (float*)alloc((size_t)G*64*4);
    unsigned* PM2= (unsigned*)alloc((size_t)G*64*4);
    float* X1    = (float*)alloc((size_t)G*128*4);
    float* X2    = (float*)alloc((size_t)G*128*4);
    (void)ws_size; (void)n_in; (void)out_size;

    const unsigned ENC_NEG_INF = 0x007FFFFFu;  // fenc(-inf)
    int nb = (N+1023)/1024;

    fill_u32_kernel<<<128,256,0,stream>>>((unsigned*)deg, 0u, N);
    fill_u32_kernel<<<128,256,0,stream>>>((unsigned*)fil, 0u, N);
    fill_u32_kernel<<<1,256,0,stream>>>((unsigned*)cnt, 0u, G);
    fill_u32_kernel<<<32,256,0,stream>>>((unsigned*)PS1, 0u, G*64);
    fill_u32_kernel<<<32,256,0,stream>>>((unsigned*)PS2, 0u, G*64);
    fill_u32_kernel<<<32,256,0,stream>>>(PM1, ENC_NEG_INF, G*64);
    fill_u32_kernel<<<32,256,0,stream>>>(PM2, ENC_NEG_INF, G*64);

    degree_kernel<<<1024,256,0,stream>>>(ei, deg, E);
    scan_ph1<<<nb,256,0,stream>>>(deg, bsum, N);
    scan_ph2<<<1,64,0,stream>>>(bsum, nb, rowptr, N, E);
    scan_ph3<<<nb,256,0,stream>>>(deg, bsum, rowptr, N);
    scatter_kernel<<<1024,256,0,stream>>>(ei, rowptr, fil, col, E);

    int nodeBlocks = (N+3)/4;
    dim3 ggemm((N+127)/128, HC/64);
    dim3 glin((N+127)/128, 1);

    // ---- layer 1 ----
    gemm_kernel<<<ggemm,256,0,stream>>>(x, g1w, nullptr, A, N, F_IN, HC, 0);
    scores_kernel<<<nodeBlocks,256,0,stream>>>(A, g1as, g1ad, SCS, SCD, N);
    aggregate_kernel<<<nodeBlocks,256,0,stream>>>(A, SCS, SCD, rowptr, col, g1b, Bb, N);
    gemm_kernel<<<glin,256,0,stream>>>(Bb, l1w, l1b, HS, N, HC, CH, 1);
    count_kernel<<<512,256,0,stream>>>(batch, cnt, N);
    pool_acc_kernel<<<2048,256,0,stream>>>(HS, batch, PS1, PM1, N);
    pool_final_kernel<<<(G*64+255)/256,256,0,stream>>>(PS1, PM1, cnt, X1, G);

    // ---- layer 2 ----
    gemm_kernel<<<ggemm,256,0,stream>>>(HS, g2w, nullptr, A, N, CH, HC, 0);
    scores_kernel<<<nodeBlocks,256,0,stream>>>(A, g2as, g2ad, SCS, SCD, N);
    aggregate_kernel<<<nodeBlocks,256,0,stream>>>(A, SCS, SCD, rowptr, col, g2b, Bb, N);
    gemm_kernel<<<glin,256,0,stream>>>(Bb, l2w, l2b, HS, N, HC, CH, 1);
    pool_acc_kernel<<<2048,256,0,stream>>>(HS, batch, PS2, PM2, N);
    pool_final_kernel<<<(G*64+255)/256,256,0,stream>>>(PS2, PM2, cnt, X2, G);

    // ---- head ----
    head_kernel<<<G,128,0,stream>>>(X1, X2, sw, sb, s1w, s1b, s2w, s2b, s3w, s3b, rw, rb, out);
}

// Round 3
// 634.729 us; speedup vs baseline: 2.5934x; 2.5934x over previous
//
#include <hip/hip_runtime.h>
#include <hip/hip_bf16.h>
#include <cstdint>

#define NEG_SLOPE 0.2f
#define HEADS 4
#define CH 64
#define HC 256
#define F_IN 260
#define KPAD1 288
#define NGRAPH 128

typedef __attribute__((ext_vector_type(8))) short bf16x8;
typedef __attribute__((ext_vector_type(4))) float f32x4;

__device__ __forceinline__ float seluf(float x){
    const float sc=1.0507009873554805f, al=1.6732632423543772f;
    return x>0.f ? sc*x : sc*al*(__expf(x)-1.f);
}
__device__ __forceinline__ unsigned fenc(float x){
    unsigned u=__float_as_uint(x);
    return (u&0x80000000u)? ~u : (u|0x80000000u);
}
__device__ __forceinline__ float fdec(unsigned e){
    unsigned u = (e&0x80000000u)? (e&0x7fffffffu) : ~e;
    return __uint_as_float(u);
}
__device__ __forceinline__ float bf2f(unsigned short u){
    return __uint_as_float(((unsigned)u)<<16);
}
__device__ __forceinline__ unsigned short f2bf_raw(float x){
    // round-to-nearest-even bf16, returned as raw u16
    unsigned u = __float_as_uint(x);
    unsigned rounded = u + 0x7fffu + ((u >> 16) & 1u);
    return (unsigned short)(rounded >> 16);
}
__device__ __forceinline__ void gload_lds16(const void* g, void* l){
    __builtin_amdgcn_global_load_lds(
        (const __attribute__((address_space(1))) void*)g,
        (__attribute__((address_space(3))) void*)l, 16, 0, 0);
}

__global__ void fill_u32_kernel(unsigned* p, unsigned v, int n){
    int i = blockIdx.x*blockDim.x + threadIdx.x;
    for (; i<n; i += gridDim.x*blockDim.x) p[i]=v;
}

__global__ void degree_kernel(const int* __restrict__ ei, int* __restrict__ deg, int E){
    int i = blockIdx.x*blockDim.x+threadIdx.x;
    for (; i<E; i+=gridDim.x*blockDim.x) atomicAdd(&deg[ei[E+i]], 1);
}

__global__ void scan_ph1(const int* __restrict__ deg, int* __restrict__ bsum, int N){
    __shared__ int sd[256];
    int base = blockIdx.x*1024;
    int t = threadIdx.x;
    int tot=0;
    for(int u=0;u<4;u++){ int i = base + t*4+u; tot += (i<N)? deg[i]:0; }
    sd[t]=tot; __syncthreads();
    for(int off=128; off; off>>=1){ if(t<off) sd[t]+=sd[t+off]; __syncthreads(); }
    if(t==0) bsum[blockIdx.x]=sd[0];
}
__global__ void scan_ph2(int* bsum, int nb, int* rowptr, int N, int E){
    if(threadIdx.x==0 && blockIdx.x==0){
        int run=0;
        for(int b=0;b<nb;b++){ int v=bsum[b]; bsum[b]=run; run+=v; }
        rowptr[N]=E;
    }
}
__global__ void scan_ph3(const int* __restrict__ deg, const int* __restrict__ bsum,
                         int* __restrict__ rowptr, int N){
    __shared__ int sd[256];
    int base = blockIdx.x*1024;
    int t = threadIdx.x;
    int v[4]; int tot=0;
    for(int u=0;u<4;u++){ int i=base+t*4+u; v[u] = (i<N)? deg[i]:0; tot+=v[u]; }
    sd[t]=tot; __syncthreads();
    for(int off=1; off<256; off<<=1){
        int add = (t>=off)? sd[t-off] : 0;
        __syncthreads();
        sd[t] += add;
        __syncthreads();
    }
    int pre = bsum[blockIdx.x] + ((t==0)?0: sd[t-1]);
    for(int u=0;u<4;u++){ int i=base+t*4+u; if(i<N){ rowptr[i]=pre; pre+=v[u]; } }
}

__global__ void scatter_kernel(const int* __restrict__ ei, const int* __restrict__ rowptr,
                               int* __restrict__ fil, int* __restrict__ col, int E){
    int i = blockIdx.x*blockDim.x+threadIdx.x;
    for(; i<E; i+=gridDim.x*blockDim.x){
        int s = ei[i], d = ei[E+i];
        int p = atomicAdd(&fil[d],1);
        col[rowptr[d]+p] = s;
    }
}

// x [N][260] f32 -> xb [N][288] bf16 zero-padded
__global__ void cvt_x_kernel(const float* __restrict__ x, __hip_bfloat16* __restrict__ xb, int N){
    int row = blockIdx.x;
    int t = threadIdx.x;
    if (row >= N) return;
    const float* src = x + (size_t)row*F_IN;
    __hip_bfloat16* dst = xb + (size_t)row*KPAD1;
    dst[t] = __float2bfloat16(src[t]);          // t in [0,256)
    if (t < 32){
        int c = 256 + t;
        dst[c] = __float2bfloat16(c < F_IN ? src[c] : 0.f);
    }
}

// w [K][NC] f32 -> wt [NC][Kpad] bf16 (transpose + zero pad)
__global__ void cvt_wT_kernel(const float* __restrict__ w, __hip_bfloat16* __restrict__ wt,
                              int K, int NC, int Kpad){
    int i = blockIdx.x*blockDim.x+threadIdx.x;
    if (i >= NC*Kpad) return;
    int n = i / Kpad, k = i - n*Kpad;
    wt[i] = __float2bfloat16(k < K ? w[(size_t)k*NC + n] : 0.f);
}

// C[M,NC] = A[M,Kpad]bf16 @ Bt[NC,Kpad]bf16^T, MFMA 16x16x32, tile 128xBN, 4 waves.
template<int BN>
__global__ __launch_bounds__(256) void mfma_gemm_kernel(
    const __hip_bfloat16* __restrict__ A, int Kpad,
    const __hip_bfloat16* __restrict__ Bt,
    const float* __restrict__ bias, int act,
    float* __restrict__ Cf, __hip_bfloat16* __restrict__ Cb,
    int M, int NC)
{
    constexpr int NF = BN/32;                 // n-frags per wave (BN=128->4, 64->2)
    constexpr int WN = BN/2;
    __shared__ __align__(16) __hip_bfloat16 As[128*32];
    __shared__ __align__(16) __hip_bfloat16 Bs[BN*32];
    int tid  = threadIdx.x;
    int lane = tid & 63;
    int w    = tid >> 6;
    int wr = w >> 1, wc = w & 1;              // 2x2 wave grid
    int row0 = blockIdx.x * 128;
    int col0 = blockIdx.y * BN;

    f32x4 acc[4][NF];
    #pragma unroll
    for (int i=0;i<4;i++)
        #pragma unroll
        for (int j=0;j<NF;j++) acc[i][j] = (f32x4){0.f,0.f,0.f,0.f};

    int lrow = lane >> 2;                     // 16 rows per wave-load segment
    int lcol = (lane & 3) * 8;                // 8 bf16 per lane chunk
    int ktiles = Kpad >> 5;

    for (int kt=0; kt<ktiles; kt++){
        int k0 = kt*32;
        // stage A: 8 segments of 16 rows, wave w does segments 2w,2w+1
        #pragma unroll
        for (int i=0;i<2;i++){
            int s = w*2 + i;
            int gr = row0 + s*16 + lrow;
            if (gr > M-1) gr = M-1;
            gload_lds16(A + (size_t)gr*Kpad + k0 + lcol, (void*)(As + s*512));
        }
        // stage B: BN/16 segments, wave w does s = w (+4)
        #pragma unroll
        for (int i=0;i<NF/2;i++){
            int s = w + i*4;
            int gn = col0 + s*16 + lrow;
            gload_lds16(Bt + (size_t)gn*Kpad + k0 + lcol, (void*)(Bs + s*512));
        }
        __syncthreads();

        bf16x8 a[4], b[NF];
        const char* AsB = (const char*)As;
        const char* BsB = (const char*)Bs;
        int koff = (lane>>4)*16;
        #pragma unroll
        for (int mt=0; mt<4; mt++){
            int arow = wr*64 + mt*16 + (lane&15);
            a[mt] = *(const bf16x8*)(AsB + arow*64 + koff);
        }
        #pragma unroll
        for (int nt=0; nt<NF; nt++){
            int brow = wc*WN + nt*16 + (lane&15);
            b[nt] = *(const bf16x8*)(BsB + brow*64 + koff);
        }
        #pragma unroll
        for (int mt=0; mt<4; mt++)
            #pragma unroll
            for (int nt=0; nt<NF; nt++)
                acc[mt][nt] = __builtin_amdgcn_mfma_f32_16x16x32_bf16(a[mt], b[nt], acc[mt][nt], 0, 0, 0);
        __syncthreads();
    }

    // epilogue: C/D layout col=lane&15, row=(lane>>4)*4+r
    #pragma unroll
    for (int mt=0; mt<4; mt++){
        #pragma unroll
        for (int r=0; r<4; r++){
            int gr = row0 + wr*64 + mt*16 + (lane>>4)*4 + r;
            if (gr >= M) continue;
            #pragma unroll
            for (int nt=0; nt<NF; nt++){
                int gc = col0 + wc*WN + nt*16 + (lane&15);
                float v = acc[mt][nt][r];
                if (bias) v += bias[gc];
                if (act)  v = seluf(v);
                if (Cf) Cf[(size_t)gr*NC + gc] = v;
                if (Cb) Cb[(size_t)gr*NC + gc] = __float2bfloat16(v);
            }
        }
    }
}

// per-node attention scores from bf16 h; lane handles 4 channels of one head
__global__ void scores_kernel(const __hip_bfloat16* __restrict__ h,
                              const float* __restrict__ asrc, const float* __restrict__ adst,
                              float* __restrict__ ss, float* __restrict__ sdv, int N){
    int node = blockIdx.x*4 + (threadIdx.x>>6);
    if (node >= N) return;
    int lane = threadIdx.x & 63;
    int hh = lane >> 4;
    int c0 = (lane & 15) * 4;
    int idx = hh*64 + c0;
    ushort4 hv = *(const ushort4*)((const unsigned short*)h + (size_t)node*HC + idx);
    float v0=bf2f(hv.x), v1=bf2f(hv.y), v2=bf2f(hv.z), v3=bf2f(hv.w);
    float ts = fmaf(v0,asrc[idx], fmaf(v1,asrc[idx+1], fmaf(v2,asrc[idx+2], v3*asrc[idx+3])));
    float td = fmaf(v0,adst[idx], fmaf(v1,adst[idx+1], fmaf(v2,adst[idx+2], v3*adst[idx+3])));
    #pragma unroll
    for (int off=1; off<16; off<<=1){
        ts += __shfl_xor(ts, off);
        td += __shfl_xor(td, off);
    }
    if ((lane&15)==0){ ss[node*4+hh]=ts; sdv[node*4+hh]=td; }
}

// one wave per dst node, online softmax; lane handles 4 channels of one head
__global__ void aggregate_kernel(const __hip_bfloat16* __restrict__ h,
                                 const float* __restrict__ ss, const float* __restrict__ sdv,
                                 const int* __restrict__ rowptr, const int* __restrict__ col,
                                 const float* __restrict__ bias,
                                 __hip_bfloat16* __restrict__ outp, int N){
    int node = blockIdx.x*4 + (threadIdx.x>>6);
    if (node >= N) return;
    int lane = threadIdx.x & 63;
    int hh = lane >> 4;
    int c0 = (lane & 15) * 4;
    int idx = hh*64 + c0;
    float ad = sdv[node*4+hh];
    float e0 = ss[node*4+hh] + ad;
    e0 = e0>0.f ? e0 : NEG_SLOPE*e0;
    float m = e0, s = 1.f;
    const unsigned short* hp = (const unsigned short*)h;
    ushort4 hv = *(const ushort4*)(hp + (size_t)node*HC + idx);
    float acc0=bf2f(hv.x), acc1=bf2f(hv.y), acc2=bf2f(hv.z), acc3=bf2f(hv.w);
    int jb = rowptr[node], je = rowptr[node+1];
    for (int j=jb; j<je; j++){
        int sc = col[j];
        ushort4 vv = *(const ushort4*)(hp + (size_t)sc*HC + idx);
        float e = ss[sc*4+hh] + ad;
        e = e>0.f ? e : NEG_SLOPE*e;
        float mn = fmaxf(m, e);
        float c1 = __expf(m - mn);
        float p  = __expf(e - mn);
        s = s*c1 + p;
        acc0 = acc0*c1 + p*bf2f(vv.x);
        acc1 = acc1*c1 + p*bf2f(vv.y);
        acc2 = acc2*c1 + p*bf2f(vv.z);
        acc3 = acc3*c1 + p*bf2f(vv.w);
        m = mn;
    }
    float inv = 1.f / s;
    unsigned short* op = (unsigned short*)outp;
    size_t ob = (size_t)node*HC + idx;
    op[ob+0] = f2bf_raw(acc0*inv + bias[idx+0]);
    op[ob+1] = f2bf_raw(acc1*inv + bias[idx+1]);
    op[ob+2] = f2bf_raw(acc2*inv + bias[idx+2]);
    op[ob+3] = f2bf_raw(acc3*inv + bias[idx+3]);
}

__global__ void count_kernel(const int* __restrict__ batch, int* __restrict__ cnt, int N){
    int i = blockIdx.x*blockDim.x + threadIdx.x;
    if (i >= N) return;
    int lane = threadIdx.x & 63;
    int g = batch[i];
    int nfull = N & ~63;
    if (i < nfull){
        int g0 = __shfl(g, 0);
        if (__all(g==g0)){ if (lane==0) atomicAdd(&cnt[g0], 64); }
        else atomicAdd(&cnt[g], 1);
    } else {
        atomicAdd(&cnt[g], 1);
    }
}

// windowed pool: block covers 128 nodes; wave handles 32 consecutive nodes, lane=channel
__global__ void pool_kernel(const float* __restrict__ hs, const int* __restrict__ batch,
                            float* __restrict__ psum, unsigned* __restrict__ pmax, int N){
    int c = threadIdx.x & 63;
    int sub = threadIdx.x >> 6;
    int n0 = blockIdx.x*128 + sub*32;
    float s = 0.f, mx = -__builtin_inff();
    int cur = -1;
    for (int j=0; j<32; j++){
        int n = n0 + j;
        if (n >= N) break;
        int g = batch[n];
        if (g != cur){
            if (cur >= 0){
                atomicAdd(&psum[cur*64+c], s);
                atomicMax(&pmax[cur*64+c], fenc(mx));
            }
            cur = g; s = 0.f; mx = -__builtin_inff();
        }
        float v = hs[(size_t)n*64 + c];
        s += v; mx = fmaxf(mx, v);
    }
    if (cur >= 0){
        atomicAdd(&psum[cur*64+c], s);
        atomicMax(&pmax[cur*64+c], fenc(mx));
    }
}

__global__ void pool_final_kernel(const float* __restrict__ psum, const unsigned* __restrict__ pmax,
                                  const int* __restrict__ cnt, float* __restrict__ x, int G){
    int i = blockIdx.x*blockDim.x+threadIdx.x;
    if (i >= G*64) return;
    int g=i>>6, c=i&63;
    float cf = fmaxf((float)cnt[g], 1.f);
    x[g*128 + c] = psum[i]/cf;
    x[g*128 + 64 + c] = fdec(pmax[i]);
}

__global__ __launch_bounds__(128) void head_kernel(
    const float* __restrict__ x1, const float* __restrict__ x2,
    const float* __restrict__ sw, const float* __restrict__ sb,
    const float* __restrict__ w1, const float* __restrict__ b1,
    const float* __restrict__ w2, const float* __restrict__ b2,
    const float* __restrict__ w3, const float* __restrict__ b3,
    const float* __restrict__ rw, const float* __restrict__ rb,
    float* __restrict__ out)
{
    int g = blockIdx.x, t = threadIdx.x;
    __shared__ float v[256], z1[128], z2[64], z3[64], z4[64];
    v[t] = x1[g*128+t];
    v[128+t] = x2[g*128+t];
    __syncthreads();
    float a = sb[t];
    for(int k=0;k<256;k++) a = fmaf(v[k], sw[k*128+t], a);
    z1[t] = a;
    __syncthreads();
    if(t<64){
        float a2 = b1[t];
        for(int k=0;k<128;k++) a2 = fmaf(z1[k], w1[k*64+t], a2);
        z2[t] = seluf(a2);
    }
    __syncthreads();
    if(t<64){
        float a3 = b2[t];
        for(int k=0;k<64;k++) a3 = fmaf(z2[k], w2[k*64+t], a3);
        z3[t] = seluf(a3);
    }
    __syncthreads();
    if(t<64){
        float a4 = b3[t];
        for(int k=0;k<64;k++) a4 = fmaf(z3[k], w3[k*64+t], a4);
        z4[t] = seluf(a4);
    }
    __syncthreads();
    if(t<32){
        float a5 = rb[t];
        for(int k=0;k<64;k++) a5 = fmaf(z4[k], rw[k*32+t], a5);
        out[g*32+t] = a5;
    }
}

extern "C" void kernel_launch(void* const* d_in, const int* in_sizes, int n_in,
                              void* d_out, int out_size, void* d_ws, size_t ws_size,
                              hipStream_t stream)
{
    const float* x    = (const float*)d_in[0];
    const int*   ei   = (const int*)d_in[1];
    const int*   batch= (const int*)d_in[2];
    const float* g1w  = (const float*)d_in[3];
    const float* g1as = (const float*)d_in[4];
    const float* g1ad = (const float*)d_in[5];
    const float* g1b  = (const float*)d_in[6];
    const float* l1w  = (const float*)d_in[7];
    const float* l1b  = (const float*)d_in[8];
    const float* g2w  = (const float*)d_in[9];
    const float* g2as = (const float*)d_in[10];
    const float* g2ad = (const float*)d_in[11];
    const float* g2b  = (const float*)d_in[12];
    const float* l2w  = (const float*)d_in[13];
    const float* l2b  = (const float*)d_in[14];
    const float* sw   = (const float*)d_in[15];
    const float* sb   = (const float*)d_in[16];
    const float* s1w  = (const float*)d_in[17];
    const float* s1b  = (const float*)d_in[18];
    const float* s2w  = (const float*)d_in[19];
    const float* s2b  = (const float*)d_in[20];
    const float* s3w  = (const float*)d_in[21];
    const float* s3b  = (const float*)d_in[22];
    const float* rw   = (const float*)d_in[23];
    const float* rb   = (const float*)d_in[24];
    float* out = (float*)d_out;

    const int N = in_sizes[0] / F_IN;
    const int E = in_sizes[1] / 2;
    const int G = NGRAPH;

    char* ws = (char*)d_ws;
    size_t off = 0;
    auto alloc = [&](size_t bytes)->void*{
        void* p = ws + off;
        off += (bytes + 255) & ~(size_t)255;
        return p;
    };
    int* deg     = (int*)alloc((size_t)2*N*4);      // deg + fil contiguous
    int* fil     = deg + N;
    int* rowptr  = (int*)alloc(((size_t)N+1)*4);
    int* col     = (int*)alloc((size_t)E*4);
    int* bsum    = (int*)alloc(1024);
    int* zpool   = (int*)alloc((size_t)(128 + 2*G*64)*4);  // cnt + PS1 + PS2
    int*   cnt = zpool;
    float* PS1 = (float*)(zpool + 128);
    float* PS2 = PS1 + G*64;
    unsigned* PM1 = (unsigned*)alloc((size_t)2*G*64*4);    // PM1 + PM2
    unsigned* PM2 = PM1 + G*64;
    float* X1    = (float*)alloc((size_t)G*128*4);
    float* X2    = (float*)alloc((size_t)G*128*4);
    __hip_bfloat16* Xb  = (__hip_bfloat16*)alloc((size_t)N*KPAD1*2);
    __hip_bfloat16* W1t = (__hip_bfloat16*)alloc((size_t)HC*KPAD1*2);
    __hip_bfloat16* L1t = (__hip_bfloat16*)alloc((size_t)CH*HC*2);
    __hip_bfloat16* W2t = (__hip_bfloat16*)alloc((size_t)HC*CH*2);
    __hip_bfloat16* L2t = (__hip_bfloat16*)alloc((size_t)CH*HC*2);
    __hip_bfloat16* Abf = (__hip_bfloat16*)alloc((size_t)N*HC*2);
    __hip_bfloat16* Bbf = (__hip_bfloat16*)alloc((size_t)N*HC*2);
    float* HSf          = (float*)alloc((size_t)N*CH*4);
    __hip_bfloat16* HSb = (__hip_bfloat16*)alloc((size_t)N*CH*2);
    float* SCS   = (float*)alloc((size_t)N*HEADS*4);
    float* SCD   = (float*)alloc((size_t)N*HEADS*4);
    (void)ws_size; (void)n_in; (void)out_size;

    const unsigned ENC_NEG_INF = 0x007FFFFFu;  // fenc(-inf)
    int nb = (N+1023)/1024;

    fill_u32_kernel<<<256,256,0,stream>>>((unsigned*)deg, 0u, 2*N);
    fill_u32_kernel<<<64,256,0,stream>>>((unsigned*)zpool, 0u, 128 + 2*G*64);
    fill_u32_kernel<<<64,256,0,stream>>>(PM1, ENC_NEG_INF, 2*G*64);

    degree_kernel<<<1024,256,0,stream>>>(ei, deg, E);
    scan_ph1<<<nb,256,0,stream>>>(deg, bsum, N);
    scan_ph2<<<1,64,0,stream>>>(bsum, nb, rowptr, N, E);
    scan_ph3<<<nb,256,0,stream>>>(deg, bsum, rowptr, N);
    scatter_kernel<<<1024,256,0,stream>>>(ei, rowptr, fil, col, E);

    cvt_x_kernel<<<N,256,0,stream>>>(x, Xb, N);
    cvt_wT_kernel<<<(HC*KPAD1+255)/256,256,0,stream>>>(g1w, W1t, F_IN, HC, KPAD1);
    cvt_wT_kernel<<<(CH*HC+255)/256,256,0,stream>>>(l1w, L1t, HC, CH, HC);
    cvt_wT_kernel<<<(HC*CH+255)/256,256,0,stream>>>(g2w, W2t, CH, HC, CH);
    cvt_wT_kernel<<<(CH*HC+255)/256,256,0,stream>>>(l2w, L2t, HC, CH, HC);

    int nodeBlocks = (N+3)/4;
    dim3 gA((N+127)/128, 2);   // NC=256, BN=128
    dim3 gL((N+127)/128, 1);   // NC=64,  BN=64

    // ---- layer 1 ----
    mfma_gemm_kernel<128><<<gA,256,0,stream>>>(Xb, KPAD1, W1t, nullptr, 0, nullptr, Abf, N, HC);
    scores_kernel<<<nodeBlocks,256,0,stream>>>(Abf, g1as, g1ad, SCS, SCD, N);
    aggregate_kernel<<<nodeBlocks,256,0,stream>>>(Abf, SCS, SCD, rowptr, col, g1b, Bbf, N);
    mfma_gemm_kernel<64><<<gL,256,0,stream>>>(Bbf, HC, L1t, l1b, 1, HSf, HSb, N, CH);
    count_kernel<<<(N+255)/256,256,0,stream>>>(batch, cnt, N);
    pool_kernel<<<(N+127)/128,256,0,stream>>>(HSf, batch, PS1, PM1, N);
    pool_final_kernel<<<(G*64+255)/256,256,0,stream>>>(PS1, PM1, cnt, X1, G);

    // ---- layer 2 ----
    mfma_gemm_kernel<128><<<gA,256,0,stream>>>(HSb, CH, W2t, nullptr, 0, nullptr, Abf, N, HC);
    scores_kernel<<<nodeBlocks,256,0,stream>>>(Abf, g2as, g2ad, SCS, SCD, N);
    aggregate_kernel<<<nodeBlocks,256,0,stream>>>(Abf, SCS, SCD, rowptr, col, g2b, Bbf, N);
    mfma_gemm_kernel<64><<<gL,256,0,stream>>>(Bbf, HC, L2t, l2b, 1, HSf, nullptr, N, CH);
    pool_kernel<<<(N+127)/128,256,0,stream>>>(HSf, batch, PS2, PM2, N);
    pool_final_kernel<<<(G*64+255)/256,256,0,stream>>>(PS2, PM2, cnt, X2, G);

    // ---- head ----
    head_kernel<<<G,128,0,stream>>>(X1, X2, sw, sb, s1w, s1b, s2w, s2b, s3w, s3b, rw, rb, out);
}